// Round 6
// baseline (415.835 us; speedup 1.0000x reference)
//
#include <hip/hip_runtime.h>
#include <cstddef>

#define NSP   56
#define NPX   3136
#define CINN  32
#define COUTN 64
#define NB    128
#define CO_PB 8
#define ROWS  7              // output rows per strip
#define NSTRIP 8             // 8 * 7 = 56
#define THR   448            // 7 waves; ty=tid>>6 (0..6), tx=tid&63 (active<56)
#define SROWS 9              // staged rows = ROWS + 2 halo
#define XCOL  68             // col 3 = left halo, 4..59 = data, 60 = right halo

// ---- pass 0: transpose W [co][c][kh][kw] -> w2 [cog][kk][c][co8] ----
__global__ __launch_bounds__(256)
void wtrans(const float* __restrict__ W, float* __restrict__ w2)
{
    int idx = blockIdx.x * 256 + threadIdx.x;
    if (idx < COUTN * CINN * 9) {
        int co_l = idx & 7;
        int t    = idx >> 3;         // (cog*9 + kk)*32 + c
        int c    = t & 31;
        t >>= 5;                     // cog*9 + kk
        int kk   = t % 9;
        int cog  = t / 9;
        w2[idx] = W[(size_t)(cog * 8 + co_l) * (CINN * 9) + c * 9 + kk];
    }
}

// ---- pass 1: conv(+bias,relu) in XLA:CPU/Eigen rounding order, y + argmax ----
__global__ __launch_bounds__(THR, 4)
void conv_emul_pass1(const float* __restrict__ x,
                     const float* __restrict__ w2,   // [8][9][32][8]
                     const float* __restrict__ bias,
                     float* __restrict__ y,          // d_out: relu(conv+bias)
                     int* __restrict__ amax)         // [NB*COUTN] argmax idx
{
    __shared__ float xs[SROWS][CINN][XCOL];   // 78336 B
    __shared__ float rv[7][CO_PB];
    __shared__ int   ri[7][CO_PB];

    const int tid = threadIdx.x;
    const int ty  = tid >> 6;          // wave id 0..6 = output row in strip
    const int tx  = tid & 63;          // 0..63, active tx<56
    const int b       = blockIdx.x >> 3;
    const int cog     = blockIdx.x & 7;
    const int co_base = cog * CO_PB;

    const float* xb = x  + (size_t)b * CINN * NPX;
    const float* wq = w2 + (size_t)cog * (9 * CINN * CO_PB);  // uniform

    // staging ownership: 448 = 32 channels x 14 float4-columns
    const int sc = tid / 14;           // channel 0..31
    const int sv = tid - sc * 14;      // float4 col 0..13
    const float* xg = xb + (size_t)sc * NPX + 4 * sv;

    // halo columns are never written by staging -> zero them ONCE
    for (int t = tid; t < SROWS * CINN * 2; t += THR) {
        int rr  = t / (CINN * 2);
        int rem = t - rr * (CINN * 2);
        int c   = rem >> 1;
        xs[rr][c][(rem & 1) ? 60 : 3] = 0.f;
    }

    float v1[CO_PB]; int i1[CO_PB];
    #pragma unroll
    for (int co = 0; co < CO_PB; ++co) { v1[co] = -1.f; i1[co] = 0; }

    float* yo = y + (size_t)(b * COUTN + co_base) * NPX;

    #pragma unroll 1
    for (int g = 0; g < NSTRIP; ++g) {
        if (g) __syncthreads();        // WAR on xs

        // stage rows 7g-1 .. 7g+7 (9 rows): 9 float4 per thread, no div
        #pragma unroll
        for (int rr = 0; rr < SROWS; ++rr) {
            int gr = 7 * g + rr - 1;
            float4 val = make_float4(0.f, 0.f, 0.f, 0.f);
            if ((unsigned)gr < (unsigned)NSP)
                val = *(const float4*)(xg + gr * NSP);
            *(float4*)&xs[rr][sc][4 + 4 * sv] = val;
        }
        __syncthreads();

        float acc[CO_PB];
        #pragma unroll
        for (int co = 0; co < CO_PB; ++co) acc[co] = 0.f;

        if (tx < NSP) {
            // EXACT ref rounding order: kh -> kw -> c (c innermost), single f32
            // acc, FMA per term; padding terms are staged zeros (exact no-ops).
            #pragma unroll
            for (int kh = 0; kh < 3; ++kh) {
                #pragma unroll
                for (int kw = 0; kw < 3; ++kw) {
                    float xv[CINN];                       // 32 batched ds_reads
                    #pragma unroll
                    for (int c = 0; c < CINN; ++c)
                        xv[c] = xs[ty + kh][c][tx + kw + 3];
                    const float* wk = wq + (kh * 3 + kw) * (CINN * CO_PB);
                    #pragma unroll
                    for (int c = 0; c < CINN; ++c) {
                        #pragma unroll
                        for (int co = 0; co < CO_PB; ++co)
                            acc[co] = fmaf(xv[c], wk[c * CO_PB + co], acc[co]);
                    }
                }
            }
            int p = (7 * g + ty) * NSP + tx;
            #pragma unroll
            for (int co = 0; co < CO_PB; ++co) {
                float v = acc[co] + bias[co_base + co];   // separate f32 add
                v = fmaxf(v, 0.f);
                yo[(size_t)co * NPX + p] = v;
                if (v > v1[co]) { v1[co] = v; i1[co] = p; }  // strict > = first idx
            }
        }
    }

    // block argmax per co: lexicographic (max val, min idx)
    #pragma unroll
    for (int co = 0; co < CO_PB; ++co) {
        float bv = v1[co]; int bi = i1[co];
        #pragma unroll
        for (int off = 32; off > 0; off >>= 1) {
            float ov = __shfl_xor(bv, off);
            int   oi = __shfl_xor(bi, off);
            if (ov > bv || (ov == bv && oi < bi)) { bv = ov; bi = oi; }
        }
        if ((tid & 63) == 0) { rv[ty][co] = bv; ri[ty][co] = bi; }
    }
    __syncthreads();
    if (tid < CO_PB) {
        float bv = rv[0][tid]; int bi = ri[0][tid];
        #pragma unroll
        for (int w = 1; w < 7; ++w) {
            float ov = rv[w][tid]; int oi = ri[w][tid];
            if (ov > bv || (ov == bv && oi < bi)) { bv = ov; bi = oi; }
        }
        amax[b * COUTN + co_base + tid] = bi;
    }
}

// ---- pass 2: in-place mask apply using the real templates input ----
__global__ __launch_bounds__(256)
void mask_apply_pass2(float* __restrict__ y,
                      const float* __restrict__ tmpl,
                      const int* __restrict__ amax)
{
    const int bc = blockIdx.x;                    // (b*64+co)
    const int idx = amax[bc];
    const float4* tp = (const float4*)(tmpl + (size_t)idx * NPX);
    float4* yp = (float4*)(y + (size_t)bc * NPX);
    #pragma unroll 1
    for (int p = threadIdx.x; p < NPX / 4; p += 256) {
        float4 a = yp[p];
        float4 t = tp[p];
        a.x *= t.x; a.y *= t.y; a.z *= t.z; a.w *= t.w;
        a.x = a.x > 0.f ? a.x : 0.f;
        a.y = a.y > 0.f ? a.y : 0.f;
        a.z = a.z > 0.f ? a.z : 0.f;
        a.w = a.w > 0.f ? a.w : 0.f;
        yp[p] = a;
    }
}

extern "C" void kernel_launch(void* const* d_in, const int* in_sizes, int n_in,
                              void* d_out, int out_size, void* d_ws, size_t ws_size,
                              hipStream_t stream)
{
    (void)in_sizes; (void)n_in; (void)ws_size; (void)out_size;
    const float* x  = (const float*)d_in[0];
    const float* W  = (const float*)d_in[1];
    const float* bi = (const float*)d_in[2];
    const float* tm = (const float*)d_in[3];
    float* out = (float*)d_out;
    int*   amax = (int*)d_ws;                           // 32 KB
    float* w2   = (float*)((char*)d_ws + 32768);        // 72 KB

    hipLaunchKernelGGL(wtrans, dim3(72), dim3(256), 0, stream, W, w2);

    dim3 grid1(NB * (COUTN / CO_PB));   // 1024 blocks
    hipLaunchKernelGGL(conv_emul_pass1, grid1, dim3(THR), 0, stream,
                       x, w2, bi, out, amax);

    dim3 grid2(NB * COUTN);             // 8192 blocks
    hipLaunchKernelGGL(mask_apply_pass2, grid2, dim3(256), 0, stream,
                       out, tm, amax);
}